// Round 6
// baseline (227.520 us; speedup 1.0000x reference)
//
#include <hip/hip_runtime.h>
#include <hip/hip_bf16.h>
#include <stdint.h>

using bf16 = __hip_bfloat16;
typedef __attribute__((ext_vector_type(8))) short short8;
typedef __attribute__((ext_vector_type(4))) float f32x4;

#define BM 128
#define BK 32

// -------- async global->LDS, 16B per lane (m97 pattern) --------
__device__ __forceinline__ void g2lds16(const void* g, void* l) {
    __builtin_amdgcn_global_load_lds(
        (const __attribute__((address_space(1))) void*)g,
        (__attribute__((address_space(3))) void*)l,
        16, 0, 0);
}

template <int N>
__device__ __forceinline__ void s_wait_vmcnt() {
    asm volatile("s_waitcnt vmcnt(%0)" :: "n"(N) : "memory");
}

__device__ __forceinline__ short f2bs(float x) {
    union { bf16 h; short s; } u;
    u.h = __float2bfloat16(x);
    return u.s;
}

// ---- LDS XOR swizzles (conflict-free fragment reads) ----
// bf16 tile [rows][32 bf16] = 4 groups/row of 8 bf16 (16B). s=(row>>1)&3.
__device__ __forceinline__ int bswz(int row, int cg) { return cg ^ ((row >> 1) & 3); }
// fp32 tile [rows][32 f32] = 8 groups/row of 4 f32 (16B). s=row&7.
__device__ __forceinline__ int fswz(int row, int cg) { return cg ^ (row & 7); }

// ---- fp32 -> bf16 64x64 tile transpose (+ optional row-major bf16 copy) ----
__global__ __launch_bounds__(256)
void transpose_cvt(const float* __restrict__ src, ushort* __restrict__ dstT,
                   ushort* __restrict__ dstN,
                   int R, int C, long sstride, long dstrideT, long dstrideN)
{
    __shared__ __align__(16) ushort t[64][72];
    const float* s = src + (size_t)blockIdx.z * sstride;
    ushort*      dT = dstT + (size_t)blockIdx.z * dstrideT;
    const int r0 = blockIdx.y * 64, c0 = blockIdx.x * 64;
    const int tid = threadIdx.x;
#pragma unroll
    for (int ii = 0; ii < 4; ++ii) {
        int idx = ii * 256 + tid;
        int r = idx >> 4, c4 = (idx & 15) * 4;
        float4 v = *(const float4*)&s[(size_t)(r0 + r) * C + c0 + c4];
        union { ushort u[4]; uint2 q; } o;
        o.u[0] = (ushort)f2bs(v.x); o.u[1] = (ushort)f2bs(v.y);
        o.u[2] = (ushort)f2bs(v.z); o.u[3] = (ushort)f2bs(v.w);
        *(uint2*)&t[r][c4] = o.q;
        if (dstN) {
            ushort* dN = dstN + (size_t)blockIdx.z * dstrideN;
            *(uint2*)&dN[(size_t)(r0 + r) * C + c0 + c4] = o.q;
        }
    }
    __syncthreads();
#pragma unroll
    for (int ii = 0; ii < 2; ++ii) {
        int idx = ii * 256 + tid;
        int c = idx >> 3, r8 = (idx & 7) * 8;
        union { ushort u[8]; uint4 v; } tmp;
#pragma unroll
        for (int j = 0; j < 8; ++j) tmp.u[j] = t[r8 + j][c];
        *(uint4*)&dT[(size_t)(c0 + c) * R + r0 + r8] = tmp.v;
    }
}

// -------- fp32 -> bf16 flat convert (4 elems/thread) --------
__global__ __launch_bounds__(256)
void cvt_f32_bf16(const float* __restrict__ in, ushort* __restrict__ out, int n4)
{
    int i = blockIdx.x * 256 + threadIdx.x;
    if (i >= n4) return;
    float4 v = ((const float4*)in)[i];
    union { ushort u[4]; uint2 q; } o;
    o.u[0] = (ushort)f2bs(v.x); o.u[1] = (ushort)f2bs(v.y);
    o.u[2] = (ushort)f2bs(v.z); o.u[3] = (ushort)f2bs(v.w);
    ((uint2*)out)[i] = o.q;
}

// -------- C = A * B^T ; A:[M][K], B:[N][K] row-major, k contiguous --------
// MODE 0: bf16 store. MODE 1: fp32 atomicAdd (split-K). MODE 2: fp32 store.
// A_F32: A operand fp32 in global (staged fp32, cvt at frag load).
// NFRAG: n-fragments (16-wide) per wave; BN = 32*NFRAG.
// Round 5: 3-buffer counted-vmcnt pipeline (distance-2 staging), one
// s_barrier per K-step, steady-state vmcnt(L) never 0. Invariants:
// per-wave vmcnt(L) => its own tile-t loads landed (tile t+1 in flight);
// barrier aggregates across waves; trailing lgkmcnt(0) before the next
// barrier closes the WAR on buf (t+2)%3 == (t-1)%3. Requires nk >= 3.
// LDS = 3 buffers (36-60 KB) -> up to 4 blocks/CU when grid provides.
template <int MODE, int A_F32, int NFRAG>
__global__ __launch_bounds__(256)
void gemm_bt(const void* __restrict__ Av, const bf16* __restrict__ B,
             void* __restrict__ Cv, int M, int N, int K, int kChunks,
             long sA, long sB, long sC)
{
    constexpr int BN  = 32 * NFRAG;
    constexpr int BSH = BN / 64;                    // B staging shots
    constexpr int ASH = A_F32 ? 4 : 2;              // A staging shots
    constexpr int L   = ASH + BSH;                  // vmcnt events per stage
    constexpr int ANE = BM * BK * (A_F32 ? 2 : 1);  // bf16 elems per A buffer
    constexpr int BNE = BN * BK;
    __shared__ __align__(16) bf16 lA[3][ANE];
    __shared__ __align__(16) bf16 lB[3][BNE];

    const int z     = blockIdx.z;
    const int batch = z / kChunks;
    const int chunk = z - batch * kChunks;
    const int kLen  = K / kChunks;
    const int k0    = chunk * kLen;

    // XCD-aware chunked swizzle of flattened (x,y); bijective since nxy%8==0
    const int gx  = gridDim.x;
    int flat = blockIdx.y * gx + blockIdx.x;
    const int cpx = (gx * gridDim.y) >> 3;
    flat = (flat & 7) * cpx + (flat >> 3);
    const int m0 = (flat / gx) * BM;
    const int n0 = (flat - (flat / gx) * gx) * BN;

    const int tid  = threadIdx.x;
    const int lane = tid & 63;
    const int wave = tid >> 6;
    const int wr   = wave >> 1, wc = wave & 1;
    const int ml   = lane & 15;
    const int q    = lane >> 4;

    // B staging pointers (swizzled)
    const bf16* Bb = B + (size_t)batch * sB;
    const bf16* bp[BSH];
#pragma unroll
    for (int s = 0; s < BSH; ++s) {
        int idx = s * 256 + tid;
        int row = idx >> 2, cg = idx & 3;
        bp[s] = Bb + (size_t)(n0 + row) * K + k0 + 8 * bswz(row, cg);
    }

    // A staging pointers (swizzled)
    const float* a32[4];
    const bf16*  a16[2];
    if constexpr (A_F32) {
        const float* Ab = (const float*)Av + (size_t)batch * sA;
#pragma unroll
        for (int s = 0; s < 4; ++s) {
            int idx = s * 256 + tid;
            int row = idx >> 3, cg = idx & 7;
            a32[s] = Ab + (size_t)(m0 + row) * K + k0 + 4 * fswz(row, cg);
        }
    } else {
        const bf16* Ab = (const bf16*)Av + (size_t)batch * sA;
#pragma unroll
        for (int s = 0; s < 2; ++s) {
            int idx = s * 256 + tid;
            int row = idx >> 2, cg = idx & 3;
            a16[s] = Ab + (size_t)(m0 + row) * K + k0 + 8 * bswz(row, cg);
        }
    }

    f32x4 acc[4][NFRAG] = {};

    // stage next tile into LDS buffer `buf`, advance pointers by BK
    auto stage = [&](int buf) {
        if constexpr (A_F32) {
            float* lAf = (float*)lA[buf];
#pragma unroll
            for (int s = 0; s < 4; ++s) {
                g2lds16(a32[s], &lAf[(s * 256 + tid) * 4]);
                a32[s] += BK;
            }
        } else {
#pragma unroll
            for (int s = 0; s < 2; ++s) {
                g2lds16(a16[s], &lA[buf][(s * 256 + tid) * 8]);
                a16[s] += BK;
            }
        }
#pragma unroll
        for (int s = 0; s < BSH; ++s) {
            g2lds16(bp[s], &lB[buf][(s * 256 + tid) * 8]);
            bp[s] += BK;
        }
    };

    // read fragments (plain loads; compiler schedules fine lgkm waits vs MFMA)
    auto frags = [&](int buf, short8 (&af)[4], short8 (&bfr)[NFRAG]) {
        const bf16* cA = lA[buf];
        const bf16* cB = lB[buf];
#pragma unroll
        for (int i = 0; i < 4; ++i) {
            const int rA = wr * 64 + i * 16 + ml;
            if constexpr (A_F32) {
                const float* lAf = (const float*)cA;
                float4 x0 = *(const float4*)&lAf[rA * 32 + 4 * fswz(rA, 2 * q)];
                float4 x1 = *(const float4*)&lAf[rA * 32 + 4 * fswz(rA, 2 * q + 1)];
                af[i][0] = f2bs(x0.x); af[i][1] = f2bs(x0.y);
                af[i][2] = f2bs(x0.z); af[i][3] = f2bs(x0.w);
                af[i][4] = f2bs(x1.x); af[i][5] = f2bs(x1.y);
                af[i][6] = f2bs(x1.z); af[i][7] = f2bs(x1.w);
            } else {
                af[i] = *(const short8*)&cA[rA * 32 + 8 * bswz(rA, q)];
            }
        }
#pragma unroll
        for (int j = 0; j < NFRAG; ++j) {
            const int rB = wc * (16 * NFRAG) + j * 16 + ml;
            bfr[j] = *(const short8*)&cB[rB * 32 + 8 * bswz(rB, q)];
        }
    };

    auto mfma = [&](short8 (&af)[4], short8 (&bfr)[NFRAG]) {
#pragma unroll
        for (int mi = 0; mi < 4; ++mi)
#pragma unroll
            for (int nj = 0; nj < NFRAG; ++nj)
                acc[mi][nj] = __builtin_amdgcn_mfma_f32_16x16x32_bf16(
                    af[mi], bfr[nj], acc[mi][nj], 0, 0, 0);
    };

    const int nk = kLen / BK;        // call sites: 8, 16, 32 (all >= 3)
    stage(0); stage(1);              // 2 tiles in flight
    int cur = 0;
    for (int t = 0; t < nk - 2; ++t) {
        s_wait_vmcnt<L>();           // tile t landed; t+1 in flight
        __builtin_amdgcn_s_barrier();
        short8 af_[4], bf_[NFRAG];
        frags(cur, af_, bf_);
        int nb = cur + 2; nb = (nb >= 3) ? nb - 3 : nb;
        stage(nb);                   // tile t+2 -> buf (t+2)%3
        mfma(af_, bf_);
        asm volatile("s_waitcnt lgkmcnt(0)" ::: "memory");
        cur = (cur == 2) ? 0 : cur + 1;
    }
    {   // t = nk-2: tiles nk-2 landed needed, nk-1 in flight
        s_wait_vmcnt<L>();
        __builtin_amdgcn_s_barrier();
        short8 af_[4], bf_[NFRAG];
        frags(cur, af_, bf_);
        mfma(af_, bf_);
        cur = (cur == 2) ? 0 : cur + 1;
    }
    {   // t = nk-1
        s_wait_vmcnt<0>();
        __builtin_amdgcn_s_barrier();
        short8 af_[4], bf_[NFRAG];
        frags(cur, af_, bf_);
        mfma(af_, bf_);
    }

    // epilogue: C/D layout col=lane&15, row=(lane>>4)*4+r (m89-verified)
#pragma unroll
    for (int mi = 0; mi < 4; ++mi)
#pragma unroll
        for (int nj = 0; nj < NFRAG; ++nj)
#pragma unroll
            for (int r = 0; r < 4; ++r) {
                int row = m0 + wr * 64 + mi * 16 + q * 4 + r;
                int col = n0 + wc * (16 * NFRAG) + nj * 16 + ml;
                if constexpr (MODE == 1) {
                    float* Cf = (float*)Cv + (size_t)batch * sC;
                    atomicAdd(&Cf[(size_t)row * N + col], acc[mi][nj][r]);
                } else if constexpr (MODE == 0) {
                    ushort* Cb = (ushort*)Cv + (size_t)batch * sC;
                    Cb[(size_t)row * N + col] = (ushort)f2bs(acc[mi][nj][r]);
                } else {
                    float* Cf = (float*)Cv + (size_t)batch * sC;
                    Cf[(size_t)row * N + col] = acc[mi][nj][r];
                }
            }
}

// ---------------------------------------------------------------
// fp32 I/O.  O = ((X W^T) X^T) X == X * (W^T (X^T X))   [associative]
//   Gf  = Xt * Xt^T    (split-K=8, fp32 atomic)    Xt = bf16(X)^T
//   Mtf = Gf * Wt^T    (split-K=4, fp32 atomic)    Wt = bf16(W)^T
//   Mt  = bf16(Mtf); O = X * Mt^T (fp32 store)
// d_out scratch: Xt @0 (16M, dead after Gf) | Gf @16M (8M) | Wt @28M (2M)
//   Mtf @0 (8M) reuses dead Xt space (memset AFTER Gf gemm, stream-ordered)
// ws: [Xb bf16 16M if ws_size>=20M] + Mt bf16 4M.
// Round 5: 3-buf pipeline; split-K 8/4 on steps 4/6; step 7 BN=64 ->
// 1024-block grids everywhere => 3-4 blocks/CU co-residency (was 1-2).
// ---------------------------------------------------------------
extern "C" void kernel_launch(void* const* d_in, const int* in_sizes, int n_in,
                              void* d_out, int out_size, void* d_ws, size_t ws_size,
                              hipStream_t stream)
{
    const int B = 2, N = 4096, D = 1024;
    const float* X = (const float*)d_in[0];   // [B][N][D] fp32
    const float* W = (const float*)d_in[1];   // [D][D]    fp32
    float* out = (float*)d_out;               // [B][N][D] fp32

    char* ob = (char*)d_out;
    char* ws = (char*)d_ws;
    ushort* Xt  = (ushort*)ob;                  // [B][D][N] bf16, 16 MiB
    float*  Mtf = (float*)ob;                   // [B][D][D] fp32,  8 MiB (after Xt dies)
    float*  Gf  = (float*)(ob + (16ll << 20));  // [B][D][D] fp32,  8 MiB
    ushort* Wt  = (ushort*)(ob + (28ll << 20)); // [D][D]    bf16,  2 MiB

    const bool bigws = ws_size >= (20ull << 20);
    ushort* Xb = bigws ? (ushort*)ws : nullptr;             // [B][N][D] bf16, 16 MiB
    ushort* Mt = (ushort*)(ws + (bigws ? (16ll << 20) : 0)); // [B][D][D] bf16, 4 MiB

    // 1) Xt[b] = bf16(X[b])^T  (+ Xb = bf16(X) row-major when ws allows)
    transpose_cvt<<<dim3(D / 64, N / 64, B), 256, 0, stream>>>(
        X, Xt, Xb, N, D, (long)N * D, (long)D * N, (long)N * D);
    // 2) Wt = bf16(W)^T
    transpose_cvt<<<dim3(D / 64, D / 64, 1), 256, 0, stream>>>(
        W, Wt, nullptr, D, D, 0, 0, 0);
    // 3) zero split-K accumulator for Gf
    (void)hipMemsetAsync(Gf, 0, (size_t)B * D * D * sizeof(float), stream);
    // 4) Gf[b] += Xt[b] * Xt[b]^T   (M=N=D, K=4096, split-K 8, BN=128)
    gemm_bt<1, 0, 4><<<dim3(D / 128, D / BM, B * 8), 256, 0, stream>>>(
        (const void*)Xt, (const bf16*)Xt, Gf, D, D, N, 8,
        (long)D * N, (long)D * N, (long)D * D);
    // 5) zero split-K accumulator for Mtf (Xt dead now; stream-ordered)
    (void)hipMemsetAsync(Mtf, 0, (size_t)B * D * D * sizeof(float), stream);
    // 6) Mtf[b] += Gf[b] * Wt^T   (M=N=D, K=D, split-K 4, BN=64, A fp32)
    gemm_bt<1, 1, 2><<<dim3(D / 64, D / BM, B * 4), 256, 0, stream>>>(
        (const void*)Gf, (const bf16*)Wt, Mtf, D, D, D, 4,
        (long)D * D, 0, (long)D * D);
    // 6b) Mt = bf16(Mtf)
    cvt_f32_bf16<<<dim3((B * D * D / 4 + 255) / 256), 256, 0, stream>>>(
        Mtf, Mt, B * D * D / 4);
    // 7) O[b] = X[b] * Mt[b]^T  (M=4096, N=D, K=D, BN=64; overwrites d_out)
    if (bigws) {
        gemm_bt<2, 0, 2><<<dim3(D / 64, N / BM, B), 256, 0, stream>>>(
            (const void*)Xb, (const bf16*)Mt, out, N, D, D, 1,
            (long)N * D, (long)D * D, (long)N * D);
    } else {
        gemm_bt<2, 1, 2><<<dim3(D / 64, N / BM, B), 256, 0, stream>>>(
            (const void*)X, (const bf16*)Mt, out, N, D, D, 1,
            (long)N * D, (long)D * D, (long)N * D);
    }
}

// Round 7
// 206.768 us; speedup vs baseline: 1.1004x; 1.1004x over previous
//
#include <hip/hip_runtime.h>
#include <hip/hip_bf16.h>
#include <stdint.h>

using bf16 = __hip_bfloat16;
typedef __attribute__((ext_vector_type(8))) short short8;
typedef __attribute__((ext_vector_type(4))) float f32x4;

#define BK 32

// -------- async global->LDS, 16B per lane (m97 pattern) --------
__device__ __forceinline__ void g2lds16(const void* g, void* l) {
    __builtin_amdgcn_global_load_lds(
        (const __attribute__((address_space(1))) void*)g,
        (__attribute__((address_space(3))) void*)l,
        16, 0, 0);
}

template <int N>
__device__ __forceinline__ void s_wait_vmcnt() {
    asm volatile("s_waitcnt vmcnt(%0)" :: "n"(N) : "memory");
}

__device__ __forceinline__ short f2bs(float x) {
    union { bf16 h; short s; } u;
    u.h = __float2bfloat16(x);
    return u.s;
}

// ---- LDS XOR swizzles (conflict-free fragment reads) ----
// bf16 tile [rows][32 bf16] = 4 groups/row of 8 bf16 (16B). s=(row>>1)&3.
__device__ __forceinline__ int bswz(int row, int cg) { return cg ^ ((row >> 1) & 3); }
// fp32 tile [rows][32 f32] = 8 groups/row of 4 f32 (16B). s=row&7.
__device__ __forceinline__ int fswz(int row, int cg) { return cg ^ (row & 7); }

// ---- fp32 -> bf16 64x64 tile transpose (+ optional row-major bf16 copy) ----
__global__ __launch_bounds__(256)
void transpose_cvt(const float* __restrict__ src, ushort* __restrict__ dstT,
                   ushort* __restrict__ dstN,
                   int R, int C, long sstride, long dstrideT, long dstrideN)
{
    __shared__ __align__(16) ushort t[64][72];
    const float* s = src + (size_t)blockIdx.z * sstride;
    ushort*      dT = dstT + (size_t)blockIdx.z * dstrideT;
    const int r0 = blockIdx.y * 64, c0 = blockIdx.x * 64;
    const int tid = threadIdx.x;
#pragma unroll
    for (int ii = 0; ii < 4; ++ii) {
        int idx = ii * 256 + tid;
        int r = idx >> 4, c4 = (idx & 15) * 4;
        float4 v = *(const float4*)&s[(size_t)(r0 + r) * C + c0 + c4];
        union { ushort u[4]; uint2 q; } o;
        o.u[0] = (ushort)f2bs(v.x); o.u[1] = (ushort)f2bs(v.y);
        o.u[2] = (ushort)f2bs(v.z); o.u[3] = (ushort)f2bs(v.w);
        *(uint2*)&t[r][c4] = o.q;
        if (dstN) {
            ushort* dN = dstN + (size_t)blockIdx.z * dstrideN;
            *(uint2*)&dN[(size_t)(r0 + r) * C + c0 + c4] = o.q;
        }
    }
    __syncthreads();
#pragma unroll
    for (int ii = 0; ii < 2; ++ii) {
        int idx = ii * 256 + tid;
        int c = idx >> 3, r8 = (idx & 7) * 8;
        union { ushort u[8]; uint4 v; } tmp;
#pragma unroll
        for (int j = 0; j < 8; ++j) tmp.u[j] = t[r8 + j][c];
        *(uint4*)&dT[(size_t)(c0 + c) * R + r0 + r8] = tmp.v;
    }
}

// -------- C = A * B^T ; single-wave 64x64 tile, NO barriers --------
// MODE 0: bf16 store. MODE 1: fp32 atomicAdd (split-K). MODE 2: fp32 store.
// A_F32: A operand fp32 in global (staged fp32, cvt at frag load).
// Round 6: 64-thread workgroups. Within one wave, vmcnt orders staging ->
// ds_read (m135), register deps order read -> MFMA, and staging a buffer
// strictly after the MFMAs that consumed it closes WAR (lgkmcnt(0) guard
// is free by then). 2 LDS buffers (16-24 KB) -> 8-10 independent waves/CU;
// per-wave stalls overlap across waves instead of convoying on s_barrier.
// Requires nk >= 2 (call sites: 32).
template <int MODE, int A_F32>
__global__ __launch_bounds__(64)
void gemm_w1(const void* __restrict__ Av, const bf16* __restrict__ B,
             void* __restrict__ Cv, int M, int N, int K, int kChunks,
             long sA, long sB, long sC)
{
    constexpr int BSH = 4;                  // B shots: 64 rows x 32 bf16
    constexpr int ASH = A_F32 ? 8 : 4;      // A shots (fp32 = 8 KB/buf)
    constexpr int L   = ASH + BSH;          // vmcnt events per stage
    constexpr int ANE = 64 * BK * (A_F32 ? 2 : 1);
    __shared__ __align__(16) bf16 lA[2][ANE];
    __shared__ __align__(16) bf16 lB[2][64 * BK];

    const int z     = blockIdx.z;
    const int batch = z / kChunks;
    const int chunk = z - batch * kChunks;
    const int kLen  = K / kChunks;
    const int k0    = chunk * kLen;

    // XCD-aware chunked swizzle of flattened (x,y); bijective since nxy%8==0
    const int gx  = gridDim.x;
    int flat = blockIdx.y * gx + blockIdx.x;
    const int cpx = (gx * gridDim.y) >> 3;
    flat = (flat & 7) * cpx + (flat >> 3);
    const int m0 = (flat / gx) * 64;
    const int n0 = (flat - (flat / gx) * gx) * 64;

    const int lane = threadIdx.x;
    const int ml   = lane & 15;
    const int q    = lane >> 4;

    // B staging pointers (swizzled)
    const bf16* Bb = B + (size_t)batch * sB;
    const bf16* bp[BSH];
#pragma unroll
    for (int s = 0; s < BSH; ++s) {
        int idx = s * 64 + lane;
        int row = idx >> 2, cg = idx & 3;
        bp[s] = Bb + (size_t)(n0 + row) * K + k0 + 8 * bswz(row, cg);
    }

    // A staging pointers (swizzled)
    const float* a32[8];
    const bf16*  a16[4];
    if constexpr (A_F32) {
        const float* Ab = (const float*)Av + (size_t)batch * sA;
#pragma unroll
        for (int s = 0; s < 8; ++s) {
            int idx = s * 64 + lane;
            int row = idx >> 3, cg = idx & 7;
            a32[s] = Ab + (size_t)(m0 + row) * K + k0 + 4 * fswz(row, cg);
        }
    } else {
        const bf16* Ab = (const bf16*)Av + (size_t)batch * sA;
#pragma unroll
        for (int s = 0; s < 4; ++s) {
            int idx = s * 64 + lane;
            int row = idx >> 2, cg = idx & 3;
            a16[s] = Ab + (size_t)(m0 + row) * K + k0 + 8 * bswz(row, cg);
        }
    }

    f32x4 acc[4][4] = {};

    auto stage = [&](int buf) {
        if constexpr (A_F32) {
            float* lAf = (float*)lA[buf];
#pragma unroll
            for (int s = 0; s < 8; ++s) {
                g2lds16(a32[s], &lAf[(s * 64 + lane) * 4]);
                a32[s] += BK;
            }
        } else {
#pragma unroll
            for (int s = 0; s < 4; ++s) {
                g2lds16(a16[s], &lA[buf][(s * 64 + lane) * 8]);
                a16[s] += BK;
            }
        }
#pragma unroll
        for (int s = 0; s < BSH; ++s) {
            g2lds16(bp[s], &lB[buf][(s * 64 + lane) * 8]);
            bp[s] += BK;
        }
    };

    auto frags = [&](int buf, short8 (&af)[4], short8 (&bfr)[4]) {
        const bf16* cA = lA[buf];
        const bf16* cB = lB[buf];
#pragma unroll
        for (int i = 0; i < 4; ++i) {
            const int rA = i * 16 + ml;
            if constexpr (A_F32) {
                const float* lAf = (const float*)cA;
                float4 x0 = *(const float4*)&lAf[rA * 32 + 4 * fswz(rA, 2 * q)];
                float4 x1 = *(const float4*)&lAf[rA * 32 + 4 * fswz(rA, 2 * q + 1)];
                af[i][0] = f2bs(x0.x); af[i][1] = f2bs(x0.y);
                af[i][2] = f2bs(x0.z); af[i][3] = f2bs(x0.w);
                af[i][4] = f2bs(x1.x); af[i][5] = f2bs(x1.y);
                af[i][6] = f2bs(x1.z); af[i][7] = f2bs(x1.w);
            } else {
                af[i] = *(const short8*)&cA[rA * 32 + 8 * bswz(rA, q)];
            }
        }
#pragma unroll
        for (int j = 0; j < 4; ++j) {
            const int rB = j * 16 + ml;
            bfr[j] = *(const short8*)&cB[rB * 32 + 8 * bswz(rB, q)];
        }
    };

    auto mfma = [&](short8 (&af)[4], short8 (&bfr)[4]) {
#pragma unroll
        for (int mi = 0; mi < 4; ++mi)
#pragma unroll
            for (int nj = 0; nj < 4; ++nj)
                acc[mi][nj] = __builtin_amdgcn_mfma_f32_16x16x32_bf16(
                    af[mi], bfr[nj], acc[mi][nj], 0, 0, 0);
    };

    const int nk = kLen / BK;            // call sites: 32
    stage(0); stage(1);                  // 2 tiles in flight (2L outstanding)
    for (int t = 0; t < nk; ++t) {
        if (t < nk - 1) s_wait_vmcnt<L>();   // tile t landed; t+1 in flight
        else            s_wait_vmcnt<0>();
        short8 af_[4], bf_[4];
        frags(t & 1, af_, bf_);
        mfma(af_, bf_);                  // consumes frags => ds_reads done
        if (t < nk - 2) {
            asm volatile("s_waitcnt lgkmcnt(0)" ::: "memory");  // ~free guard
            stage(t & 1);                // tile t+2 overwrites consumed buf
        }
    }

    // epilogue: C/D layout col=lane&15, row=(lane>>4)*4+r (m89-verified)
#pragma unroll
    for (int mi = 0; mi < 4; ++mi)
#pragma unroll
        for (int nj = 0; nj < 4; ++nj)
#pragma unroll
            for (int r = 0; r < 4; ++r) {
                int row = m0 + mi * 16 + q * 4 + r;
                int col = n0 + nj * 16 + ml;
                if constexpr (MODE == 1) {
                    float* Cf = (float*)Cv + (size_t)batch * sC;
                    atomicAdd(&Cf[(size_t)row * N + col], acc[mi][nj][r]);
                } else if constexpr (MODE == 0) {
                    ushort* Cb = (ushort*)Cv + (size_t)batch * sC;
                    Cb[(size_t)row * N + col] = (ushort)f2bs(acc[mi][nj][r]);
                } else {
                    float* Cf = (float*)Cv + (size_t)batch * sC;
                    Cf[(size_t)row * N + col] = acc[mi][nj][r];
                }
            }
}

// ---------------------------------------------------------------
// fp32 I/O.  O = ((X W^T) X^T) X == X * (W^T (X^T X))   [associative]
//   Gf = Xt * Xt^T   (split-K=4, fp32 atomic)     Xt = bf16(X)^T
//   Mt = Gf * Wt^T   (A fp32 staged, bf16 store)  Wt = bf16(W)^T
//   O  = X * Mt^T    (fp32 store; A = Xb bf16 if ws fits, else X fp32)
// d_out scratch (dead before step 7 overwrites):
//   Xt bf16 @0 (16M) | Gf f32 @16M (8M) | Wt @28M (2M)
// ws: [Xb bf16 16M if ws_size>=20M] + Mt bf16 4M.
// Round 6: all GEMMs on barrier-free 1-wave 64x64 kernel; split-K back
// to 4 (R5's sk=8 doubled atomic WRITE traffic, 46->73 us).
// ---------------------------------------------------------------
extern "C" void kernel_launch(void* const* d_in, const int* in_sizes, int n_in,
                              void* d_out, int out_size, void* d_ws, size_t ws_size,
                              hipStream_t stream)
{
    const int B = 2, N = 4096, D = 1024;
    const float* X = (const float*)d_in[0];   // [B][N][D] fp32
    const float* W = (const float*)d_in[1];   // [D][D]    fp32
    float* out = (float*)d_out;               // [B][N][D] fp32

    char* ob = (char*)d_out;
    char* ws = (char*)d_ws;
    ushort* Xt = (ushort*)ob;                  // [B][D][N] bf16, 16 MiB
    float*  Gf = (float*)(ob + (16ll << 20));  // [B][D][D] fp32,  8 MiB
    ushort* Wt = (ushort*)(ob + (28ll << 20)); // [D][D]    bf16,  2 MiB

    const bool bigws = ws_size >= (20ull << 20);
    ushort* Xb = bigws ? (ushort*)ws : nullptr;             // [B][N][D] bf16, 16 MiB
    ushort* Mt = (ushort*)(ws + (bigws ? (16ll << 20) : 0)); // [B][D][D] bf16, 4 MiB

    // 1) Xt[b] = bf16(X[b])^T  (+ Xb = bf16(X) row-major when ws allows)
    transpose_cvt<<<dim3(D / 64, N / 64, B), 256, 0, stream>>>(
        X, Xt, Xb, N, D, (long)N * D, (long)D * N, (long)N * D);
    // 2) Wt = bf16(W)^T
    transpose_cvt<<<dim3(D / 64, D / 64, 1), 256, 0, stream>>>(
        W, Wt, nullptr, D, D, 0, 0, 0);
    // 3) zero split-K accumulator
    (void)hipMemsetAsync(Gf, 0, (size_t)B * D * D * sizeof(float), stream);
    // 4) Gf[b] += Xt[b] * Xt[b]^T   (M=N=D, K=4096, split-K 4; 2048 blocks)
    gemm_w1<1, 0><<<dim3(D / 64, D / 64, B * 4), 64, 0, stream>>>(
        (const void*)Xt, (const bf16*)Xt, Gf, D, D, N, 4,
        (long)D * N, (long)D * N, (long)D * D);
    // 6) Mt[b] = Gf[b] * Wt^T   (M=N=K=D, A fp32 staged; 512 blocks)
    gemm_w1<0, 1><<<dim3(D / 64, D / 64, B), 64, 0, stream>>>(
        (const void*)Gf, (const bf16*)Wt, Mt, D, D, D, 1,
        (long)D * D, 0, (long)D * D);
    // 7) O[b] = X[b] * Mt[b]^T  (M=4096, N=D, K=D; 2048 blocks)
    if (bigws) {
        gemm_w1<2, 0><<<dim3(D / 64, N / 64, B), 64, 0, stream>>>(
            (const void*)Xb, (const bf16*)Mt, out, N, D, D, 1,
            (long)N * D, (long)D * D, (long)N * D);
    } else {
        gemm_w1<2, 1><<<dim3(D / 64, N / 64, B), 64, 0, stream>>>(
            (const void*)X, (const bf16*)Mt, out, N, D, D, 1,
            (long)N * D, (long)D * D, (long)N * D);
    }
}

// Round 8
// 202.201 us; speedup vs baseline: 1.1252x; 1.0226x over previous
//
#include <hip/hip_runtime.h>
#include <hip/hip_bf16.h>
#include <stdint.h>

using bf16 = __hip_bfloat16;
typedef __attribute__((ext_vector_type(8))) short short8;
typedef __attribute__((ext_vector_type(4))) float f32x4;

#define BM 128
#define BK 32

// -------- async global->LDS, 16B per lane (m97 pattern) --------
__device__ __forceinline__ void g2lds16(const void* g, void* l) {
    __builtin_amdgcn_global_load_lds(
        (const __attribute__((address_space(1))) void*)g,
        (__attribute__((address_space(3))) void*)l,
        16, 0, 0);
}

template <int N>
__device__ __forceinline__ void s_wait_vmcnt() {
    asm volatile("s_waitcnt vmcnt(%0)" :: "n"(N) : "memory");
}

__device__ __forceinline__ short f2bs(float x) {
    union { bf16 h; short s; } u;
    u.h = __float2bfloat16(x);
    return u.s;
}

// ---- LDS XOR swizzles (conflict-free fragment reads) ----
// bf16 tile [rows][32 bf16] = 4 groups/row of 8 bf16 (16B). s=(row>>1)&3.
__device__ __forceinline__ int bswz(int row, int cg) { return cg ^ ((row >> 1) & 3); }
// fp32 tile [rows][32 f32] = 8 groups/row of 4 f32 (16B). s=row&7.
__device__ __forceinline__ int fswz(int row, int cg) { return cg ^ (row & 7); }

// ---- fp32 -> bf16 64x64 tile transpose (+ optional row-major bf16 copy) ----
__global__ __launch_bounds__(256)
void transpose_cvt(const float* __restrict__ src, ushort* __restrict__ dstT,
                   ushort* __restrict__ dstN,
                   int R, int C, long sstride, long dstrideT, long dstrideN)
{
    __shared__ __align__(16) ushort t[64][72];
    const float* s = src + (size_t)blockIdx.z * sstride;
    ushort*      dT = dstT + (size_t)blockIdx.z * dstrideT;
    const int r0 = blockIdx.y * 64, c0 = blockIdx.x * 64;
    const int tid = threadIdx.x;
#pragma unroll
    for (int ii = 0; ii < 4; ++ii) {
        int idx = ii * 256 + tid;
        int r = idx >> 4, c4 = (idx & 15) * 4;
        float4 v = *(const float4*)&s[(size_t)(r0 + r) * C + c0 + c4];
        union { ushort u[4]; uint2 q; } o;
        o.u[0] = (ushort)f2bs(v.x); o.u[1] = (ushort)f2bs(v.y);
        o.u[2] = (ushort)f2bs(v.z); o.u[3] = (ushort)f2bs(v.w);
        *(uint2*)&t[r][c4] = o.q;
        if (dstN) {
            ushort* dN = dstN + (size_t)blockIdx.z * dstrideN;
            *(uint2*)&dN[(size_t)(r0 + r) * C + c0 + c4] = o.q;
        }
    }
    __syncthreads();
#pragma unroll
    for (int ii = 0; ii < 2; ++ii) {
        int idx = ii * 256 + tid;
        int c = idx >> 3, r8 = (idx & 7) * 8;
        union { ushort u[8]; uint4 v; } tmp;
#pragma unroll
        for (int j = 0; j < 8; ++j) tmp.u[j] = t[r8 + j][c];
        *(uint4*)&dT[(size_t)(c0 + c) * R + r0 + r8] = tmp.v;
    }
}

// -------- fp32 -> bf16 flat convert (4 elems/thread) --------
__global__ __launch_bounds__(256)
void cvt_f32_bf16(const float* __restrict__ in, ushort* __restrict__ out, int n4)
{
    int i = blockIdx.x * 256 + threadIdx.x;
    if (i >= n4) return;
    float4 v = ((const float4*)in)[i];
    union { ushort u[4]; uint2 q; } o;
    o.u[0] = (ushort)f2bs(v.x); o.u[1] = (ushort)f2bs(v.y);
    o.u[2] = (ushort)f2bs(v.z); o.u[3] = (ushort)f2bs(v.w);
    ((uint2*)out)[i] = o.q;
}

// -------- C = A * B^T ; A:[M][K], B:[N][K] row-major, k contiguous --------
// MODE 0: bf16 store. MODE 1: fp32 atomicAdd (split-K). MODE 2: fp32 store.
// A_F32: A operand fp32 in global (staged fp32, cvt at frag load).
// NFRAG: n-fragments (16-wide) per wave; BN = 32*NFRAG.
// 3-buffer counted-vmcnt pipeline (distance-2 staging), one s_barrier per
// K-step, steady-state vmcnt(L) never 0 (proven R5/R6-pass). Round 7:
// geometry only — NFRAG=2 grids (1024 blocks) x 36KB LDS => 4 blocks/CU
// co-residency with the counted-vmcnt schedule (the untested matrix cell).
template <int MODE, int A_F32, int NFRAG>
__global__ __launch_bounds__(256)
void gemm_bt(const void* __restrict__ Av, const bf16* __restrict__ B,
             void* __restrict__ Cv, int M, int N, int K, int kChunks,
             long sA, long sB, long sC)
{
    constexpr int BN  = 32 * NFRAG;
    constexpr int BSH = (BN * BK * 2) / (256 * 16); // B staging shots
    constexpr int ASH = A_F32 ? 4 : 2;              // A staging shots
    constexpr int L   = ASH + BSH;                  // vmcnt events per stage
    constexpr int ANE = BM * BK * (A_F32 ? 2 : 1);  // bf16 elems per A buffer
    constexpr int BNE = BN * BK;
    __shared__ __align__(16) bf16 lA[3][ANE];
    __shared__ __align__(16) bf16 lB[3][BNE];

    const int z     = blockIdx.z;
    const int batch = z / kChunks;
    const int chunk = z - batch * kChunks;
    const int kLen  = K / kChunks;
    const int k0    = chunk * kLen;

    // XCD-aware chunked swizzle of flattened (x,y); bijective since nxy%8==0
    const int gx  = gridDim.x;
    int flat = blockIdx.y * gx + blockIdx.x;
    const int cpx = (gx * gridDim.y) >> 3;
    flat = (flat & 7) * cpx + (flat >> 3);
    const int m0 = (flat / gx) * BM;
    const int n0 = (flat - (flat / gx) * gx) * BN;

    const int tid  = threadIdx.x;
    const int lane = tid & 63;
    const int wave = tid >> 6;
    const int wr   = wave >> 1, wc = wave & 1;
    const int ml   = lane & 15;
    const int q    = lane >> 4;

    // B staging pointers (swizzled)
    const bf16* Bb = B + (size_t)batch * sB;
    const bf16* bp[BSH];
#pragma unroll
    for (int s = 0; s < BSH; ++s) {
        int idx = s * 256 + tid;
        int row = idx >> 2, cg = idx & 3;
        bp[s] = Bb + (size_t)(n0 + row) * K + k0 + 8 * bswz(row, cg);
    }

    // A staging pointers (swizzled)
    const float* a32[4];
    const bf16*  a16[2];
    if constexpr (A_F32) {
        const float* Ab = (const float*)Av + (size_t)batch * sA;
#pragma unroll
        for (int s = 0; s < 4; ++s) {
            int idx = s * 256 + tid;
            int row = idx >> 3, cg = idx & 7;
            a32[s] = Ab + (size_t)(m0 + row) * K + k0 + 4 * fswz(row, cg);
        }
    } else {
        const bf16* Ab = (const bf16*)Av + (size_t)batch * sA;
#pragma unroll
        for (int s = 0; s < 2; ++s) {
            int idx = s * 256 + tid;
            int row = idx >> 2, cg = idx & 3;
            a16[s] = Ab + (size_t)(m0 + row) * K + k0 + 8 * bswz(row, cg);
        }
    }

    f32x4 acc[4][NFRAG] = {};

    // stage next tile into LDS buffer `buf`, advance pointers by BK
    auto stage = [&](int buf) {
        if constexpr (A_F32) {
            float* lAf = (float*)lA[buf];
#pragma unroll
            for (int s = 0; s < 4; ++s) {
                g2lds16(a32[s], &lAf[(s * 256 + tid) * 4]);
                a32[s] += BK;
            }
        } else {
#pragma unroll
            for (int s = 0; s < 2; ++s) {
                g2lds16(a16[s], &lA[buf][(s * 256 + tid) * 8]);
                a16[s] += BK;
            }
        }
#pragma unroll
        for (int s = 0; s < BSH; ++s) {
            g2lds16(bp[s], &lB[buf][(s * 256 + tid) * 8]);
            bp[s] += BK;
        }
    };

    // read fragments (plain loads; compiler schedules fine lgkm waits vs MFMA)
    auto frags = [&](int buf, short8 (&af)[4], short8 (&bfr)[NFRAG]) {
        const bf16* cA = lA[buf];
        const bf16* cB = lB[buf];
#pragma unroll
        for (int i = 0; i < 4; ++i) {
            const int rA = wr * 64 + i * 16 + ml;
            if constexpr (A_F32) {
                const float* lAf = (const float*)cA;
                float4 x0 = *(const float4*)&lAf[rA * 32 + 4 * fswz(rA, 2 * q)];
                float4 x1 = *(const float4*)&lAf[rA * 32 + 4 * fswz(rA, 2 * q + 1)];
                af[i][0] = f2bs(x0.x); af[i][1] = f2bs(x0.y);
                af[i][2] = f2bs(x0.z); af[i][3] = f2bs(x0.w);
                af[i][4] = f2bs(x1.x); af[i][5] = f2bs(x1.y);
                af[i][6] = f2bs(x1.z); af[i][7] = f2bs(x1.w);
            } else {
                af[i] = *(const short8*)&cA[rA * 32 + 8 * bswz(rA, q)];
            }
        }
#pragma unroll
        for (int j = 0; j < NFRAG; ++j) {
            const int rB = wc * (16 * NFRAG) + j * 16 + ml;
            bfr[j] = *(const short8*)&cB[rB * 32 + 8 * bswz(rB, q)];
        }
    };

    auto mfma = [&](short8 (&af)[4], short8 (&bfr)[NFRAG]) {
#pragma unroll
        for (int mi = 0; mi < 4; ++mi)
#pragma unroll
            for (int nj = 0; nj < NFRAG; ++nj)
                acc[mi][nj] = __builtin_amdgcn_mfma_f32_16x16x32_bf16(
                    af[mi], bfr[nj], acc[mi][nj], 0, 0, 0);
    };

    const int nk = kLen / BK;        // call sites: 16, 32 (all >= 3)
    stage(0); stage(1);              // 2 tiles in flight
    int cur = 0;
    for (int t = 0; t < nk - 2; ++t) {
        s_wait_vmcnt<L>();           // tile t landed; t+1 in flight
        __builtin_amdgcn_s_barrier();
        short8 af_[4], bf_[NFRAG];
        frags(cur, af_, bf_);
        int nb = cur + 2; nb = (nb >= 3) ? nb - 3 : nb;
        stage(nb);                   // tile t+2 -> buf (t+2)%3
        mfma(af_, bf_);
        asm volatile("s_waitcnt lgkmcnt(0)" ::: "memory");
        cur = (cur == 2) ? 0 : cur + 1;
    }
    {   // t = nk-2: tile nk-2 landed, nk-1 in flight
        s_wait_vmcnt<L>();
        __builtin_amdgcn_s_barrier();
        short8 af_[4], bf_[NFRAG];
        frags(cur, af_, bf_);
        mfma(af_, bf_);
        cur = (cur == 2) ? 0 : cur + 1;
    }
    {   // t = nk-1
        s_wait_vmcnt<0>();
        __builtin_amdgcn_s_barrier();
        short8 af_[4], bf_[NFRAG];
        frags(cur, af_, bf_);
        mfma(af_, bf_);
    }

    // epilogue: C/D layout col=lane&15, row=(lane>>4)*4+r (m89-verified)
#pragma unroll
    for (int mi = 0; mi < 4; ++mi)
#pragma unroll
        for (int nj = 0; nj < NFRAG; ++nj)
#pragma unroll
            for (int r = 0; r < 4; ++r) {
                int row = m0 + wr * 64 + mi * 16 + q * 4 + r;
                int col = n0 + wc * (16 * NFRAG) + nj * 16 + ml;
                if constexpr (MODE == 1) {
                    float* Cf = (float*)Cv + (size_t)batch * sC;
                    atomicAdd(&Cf[(size_t)row * N + col], acc[mi][nj][r]);
                } else if constexpr (MODE == 0) {
                    ushort* Cb = (ushort*)Cv + (size_t)batch * sC;
                    Cb[(size_t)row * N + col] = (ushort)f2bs(acc[mi][nj][r]);
                } else {
                    float* Cf = (float*)Cv + (size_t)batch * sC;
                    Cf[(size_t)row * N + col] = acc[mi][nj][r];
                }
            }
}

// ---------------------------------------------------------------
// fp32 I/O.  O = ((X W^T) X^T) X == X * (W^T (X^T X))   [associative]
//   Gf  = Xt * Xt^T    (split-K=4, fp32 atomic)    Xt = bf16(X)^T
//   Mtf = Gf * Wt^T    (split-K=2, fp32 atomic)    Wt = bf16(W)^T
//   Mt  = bf16(Mtf); O = X * Mt^T (fp32 store)
// d_out scratch: Xt @0 (16M, dead after Gf) | Gf @16M (8M) | Wt @28M (2M)
//   Mtf @0 (8M) reuses dead Xt space (memset AFTER Gf gemm, stream-ordered)
// ws: [Xb bf16 16M if ws_size>=20M] + Mt bf16 4M.
// Round 7: counted-vmcnt pipeline x 4 blocks/CU geometry — BN=64 grids
// (1024 blocks for steps 4/7), split-K 4/2. The MLP x schedule cell.
// ---------------------------------------------------------------
extern "C" void kernel_launch(void* const* d_in, const int* in_sizes, int n_in,
                              void* d_out, int out_size, void* d_ws, size_t ws_size,
                              hipStream_t stream)
{
    const int B = 2, N = 4096, D = 1024;
    const float* X = (const float*)d_in[0];   // [B][N][D] fp32
    const float* W = (const float*)d_in[1];   // [D][D]    fp32
    float* out = (float*)d_out;               // [B][N][D] fp32

    char* ob = (char*)d_out;
    char* ws = (char*)d_ws;
    ushort* Xt  = (ushort*)ob;                  // [B][D][N] bf16, 16 MiB
    float*  Mtf = (float*)ob;                   // [B][D][D] fp32,  8 MiB (after Xt dies)
    float*  Gf  = (float*)(ob + (16ll << 20));  // [B][D][D] fp32,  8 MiB
    ushort* Wt  = (ushort*)(ob + (28ll << 20)); // [D][D]    bf16,  2 MiB

    const bool bigws = ws_size >= (20ull << 20);
    ushort* Xb = bigws ? (ushort*)ws : nullptr;             // [B][N][D] bf16, 16 MiB
    ushort* Mt = (ushort*)(ws + (bigws ? (16ll << 20) : 0)); // [B][D][D] bf16, 4 MiB

    // 1) Xt[b] = bf16(X[b])^T  (+ Xb = bf16(X) row-major when ws allows)
    transpose_cvt<<<dim3(D / 64, N / 64, B), 256, 0, stream>>>(
        X, Xt, Xb, N, D, (long)N * D, (long)D * N, (long)N * D);
    // 2) Wt = bf16(W)^T
    transpose_cvt<<<dim3(D / 64, D / 64, 1), 256, 0, stream>>>(
        W, Wt, nullptr, D, D, 0, 0, 0);
    // 3) zero split-K accumulator for Gf
    (void)hipMemsetAsync(Gf, 0, (size_t)B * D * D * sizeof(float), stream);
    // 4) Gf[b] += Xt[b] * Xt[b]^T  (M=N=D, K=4096, sk=4, BN=64; 1024 blocks)
    gemm_bt<1, 0, 2><<<dim3(D / 64, D / BM, B * 4), 256, 0, stream>>>(
        (const void*)Xt, (const bf16*)Xt, Gf, D, D, N, 4,
        (long)D * N, (long)D * N, (long)D * D);
    // 5) zero split-K accumulator for Mtf (Xt dead now; stream-ordered)
    (void)hipMemsetAsync(Mtf, 0, (size_t)B * D * D * sizeof(float), stream);
    // 6) Mtf[b] += Gf[b] * Wt^T  (M=N=D, K=D, sk=2, BN=64, A fp32; 512 blocks)
    gemm_bt<1, 1, 2><<<dim3(D / 64, D / BM, B * 2), 256, 0, stream>>>(
        (const void*)Gf, (const bf16*)Wt, Mtf, D, D, D, 2,
        (long)D * D, 0, (long)D * D);
    // 6b) Mt = bf16(Mtf)
    cvt_f32_bf16<<<dim3((B * D * D / 4 + 255) / 256), 256, 0, stream>>>(
        Mtf, Mt, B * D * D / 4);
    // 7) O[b] = X[b] * Mt[b]^T  (M=4096, N=D, K=D, BN=64; 1024 blocks)
    if (bigws) {
        gemm_bt<2, 0, 2><<<dim3(D / 64, N / BM, B), 256, 0, stream>>>(
            (const void*)Xb, (const bf16*)Mt, out, N, D, D, 1,
            (long)N * D, (long)D * D, (long)N * D);
    } else {
        gemm_bt<2, 1, 2><<<dim3(D / 64, N / BM, B), 256, 0, stream>>>(
            (const void*)X, (const bf16*)Mt, out, N, D, D, 1,
            (long)N * D, (long)D * D, (long)N * D);
    }
}

// Round 9
// 175.431 us; speedup vs baseline: 1.2969x; 1.1526x over previous
//
#include <hip/hip_runtime.h>
#include <hip/hip_bf16.h>
#include <stdint.h>

using bf16 = __hip_bfloat16;
typedef __attribute__((ext_vector_type(8))) short short8;
typedef __attribute__((ext_vector_type(4))) float f32x4;

#define BM 128
#define BK 32

// -------- async global->LDS, 16B per lane (m97 pattern) --------
__device__ __forceinline__ void g2lds16(const void* g, void* l) {
    __builtin_amdgcn_global_load_lds(
        (const __attribute__((address_space(1))) void*)g,
        (__attribute__((address_space(3))) void*)l,
        16, 0, 0);
}

template <int N>
__device__ __forceinline__ void s_wait_vmcnt() {
    asm volatile("s_waitcnt vmcnt(%0)" :: "n"(N) : "memory");
}

__device__ __forceinline__ short f2bs(float x) {
    union { bf16 h; short s; } u;
    u.h = __float2bfloat16(x);
    return u.s;
}

// ---- LDS XOR swizzles (conflict-free fragment reads) ----
// bf16 tile [rows][32 bf16] = 4 groups/row of 8 bf16 (16B). s=(row>>1)&3.
__device__ __forceinline__ int bswz(int row, int cg) { return cg ^ ((row >> 1) & 3); }
// fp32 tile [rows][32 f32] = 8 groups/row of 4 f32 (16B). s=row&7.
__device__ __forceinline__ int fswz(int row, int cg) { return cg ^ (row & 7); }

// ---- fp32 -> bf16 64x64 tile transpose (+ optional row-major bf16 copy) ----
__global__ __launch_bounds__(256)
void transpose_cvt(const float* __restrict__ src, ushort* __restrict__ dstT,
                   ushort* __restrict__ dstN,
                   int R, int C, long sstride, long dstrideT, long dstrideN)
{
    __shared__ __align__(16) ushort t[64][72];
    const float* s = src + (size_t)blockIdx.z * sstride;
    ushort*      dT = dstT + (size_t)blockIdx.z * dstrideT;
    const int r0 = blockIdx.y * 64, c0 = blockIdx.x * 64;
    const int tid = threadIdx.x;
#pragma unroll
    for (int ii = 0; ii < 4; ++ii) {
        int idx = ii * 256 + tid;
        int r = idx >> 4, c4 = (idx & 15) * 4;
        float4 v = *(const float4*)&s[(size_t)(r0 + r) * C + c0 + c4];
        union { ushort u[4]; uint2 q; } o;
        o.u[0] = (ushort)f2bs(v.x); o.u[1] = (ushort)f2bs(v.y);
        o.u[2] = (ushort)f2bs(v.z); o.u[3] = (ushort)f2bs(v.w);
        *(uint2*)&t[r][c4] = o.q;
        if (dstN) {
            ushort* dN = dstN + (size_t)blockIdx.z * dstrideN;
            *(uint2*)&dN[(size_t)(r0 + r) * C + c0 + c4] = o.q;
        }
    }
    __syncthreads();
#pragma unroll
    for (int ii = 0; ii < 2; ++ii) {
        int idx = ii * 256 + tid;
        int c = idx >> 3, r8 = (idx & 7) * 8;
        union { ushort u[8]; uint4 v; } tmp;
#pragma unroll
        for (int j = 0; j < 8; ++j) tmp.u[j] = t[r8 + j][c];
        *(uint4*)&dT[(size_t)(c0 + c) * R + r0 + r8] = tmp.v;
    }
}

// -------- C = A * B^T ; A:[M][K], B:[N][K] row-major, k contiguous --------
// MODE 0: bf16 store. MODE 1: fp32 atomicAdd (split-K). MODE 2: fp32 store.
// A_F32: A operand fp32 in global (staged fp32, cvt at frag load).
// NFRAG: n-fragments (16-wide) per wave; BN = 32*NFRAG.
// 3-buffer counted-vmcnt pipeline (R5-verified). Round 8: z-aware
// XCD-CONTIGUOUS work remap — hardware wgid round-robins over 8 XCDs
// (wgid%8); remap gives XCD k the contiguous logical range
// [k*nwg/8, (k+1)*nwg/8), so each XCD's L2 holds ONE coherent working
// set (e.g. step 4: one (batch,chunk) = a single 2MB Xt slice, A==B).
// Bijective when nwg%8==0 (call sites: 512/256/512).
template <int MODE, int A_F32, int NFRAG>
__global__ __launch_bounds__(256)
void gemm_bt(const void* __restrict__ Av, const bf16* __restrict__ B,
             void* __restrict__ Cv, int M, int N, int K, int kChunks,
             long sA, long sB, long sC)
{
    constexpr int BN  = 32 * NFRAG;
    constexpr int BSH = (BN * BK * 2) / (256 * 16); // B staging shots
    constexpr int ASH = A_F32 ? 4 : 2;              // A staging shots
    constexpr int L   = ASH + BSH;                  // vmcnt events per stage
    constexpr int ANE = BM * BK * (A_F32 ? 2 : 1);  // bf16 elems per A buffer
    constexpr int BNE = BN * BK;
    __shared__ __align__(16) bf16 lA[3][ANE];
    __shared__ __align__(16) bf16 lB[3][BNE];

    // ---- XCD-contiguous remap (z-aware) ----
    const int gx   = gridDim.x, gy = gridDim.y;
    const int nwg  = gx * gy * gridDim.z;
    const int wgid = (blockIdx.z * gy + blockIdx.y) * gx + blockIdx.x;
    const int lid  = (wgid & 7) * (nwg >> 3) + (wgid >> 3);
    const int pz   = gx * gy;
    const int z    = lid / pz;
    const int rem  = lid - z * pz;
    const int my   = rem / gx;
    const int m0   = my * BM;
    const int n0   = (rem - my * gx) * BN;

    const int batch = z / kChunks;
    const int chunk = z - batch * kChunks;
    const int kLen  = K / kChunks;
    const int k0    = chunk * kLen;

    const int tid  = threadIdx.x;
    const int lane = tid & 63;
    const int wave = tid >> 6;
    const int wr   = wave >> 1, wc = wave & 1;
    const int ml   = lane & 15;
    const int q    = lane >> 4;

    // B staging pointers (swizzled)
    const bf16* Bb = B + (size_t)batch * sB;
    const bf16* bp[BSH];
#pragma unroll
    for (int s = 0; s < BSH; ++s) {
        int idx = s * 256 + tid;
        int row = idx >> 2, cg = idx & 3;
        bp[s] = Bb + (size_t)(n0 + row) * K + k0 + 8 * bswz(row, cg);
    }

    // A staging pointers (swizzled)
    const float* a32[4];
    const bf16*  a16[2];
    if constexpr (A_F32) {
        const float* Ab = (const float*)Av + (size_t)batch * sA;
#pragma unroll
        for (int s = 0; s < 4; ++s) {
            int idx = s * 256 + tid;
            int row = idx >> 3, cg = idx & 7;
            a32[s] = Ab + (size_t)(m0 + row) * K + k0 + 4 * fswz(row, cg);
        }
    } else {
        const bf16* Ab = (const bf16*)Av + (size_t)batch * sA;
#pragma unroll
        for (int s = 0; s < 2; ++s) {
            int idx = s * 256 + tid;
            int row = idx >> 2, cg = idx & 3;
            a16[s] = Ab + (size_t)(m0 + row) * K + k0 + 8 * bswz(row, cg);
        }
    }

    f32x4 acc[4][NFRAG] = {};

    // stage next tile into LDS buffer `buf`, advance pointers by BK
    auto stage = [&](int buf) {
        if constexpr (A_F32) {
            float* lAf = (float*)lA[buf];
#pragma unroll
            for (int s = 0; s < 4; ++s) {
                g2lds16(a32[s], &lAf[(s * 256 + tid) * 4]);
                a32[s] += BK;
            }
        } else {
#pragma unroll
            for (int s = 0; s < 2; ++s) {
                g2lds16(a16[s], &lA[buf][(s * 256 + tid) * 8]);
                a16[s] += BK;
            }
        }
#pragma unroll
        for (int s = 0; s < BSH; ++s) {
            g2lds16(bp[s], &lB[buf][(s * 256 + tid) * 8]);
            bp[s] += BK;
        }
    };

    // read fragments (plain loads; compiler schedules fine lgkm waits vs MFMA)
    auto frags = [&](int buf, short8 (&af)[4], short8 (&bfr)[NFRAG]) {
        const bf16* cA = lA[buf];
        const bf16* cB = lB[buf];
#pragma unroll
        for (int i = 0; i < 4; ++i) {
            const int rA = wr * 64 + i * 16 + ml;
            if constexpr (A_F32) {
                const float* lAf = (const float*)cA;
                float4 x0 = *(const float4*)&lAf[rA * 32 + 4 * fswz(rA, 2 * q)];
                float4 x1 = *(const float4*)&lAf[rA * 32 + 4 * fswz(rA, 2 * q + 1)];
                af[i][0] = f2bs(x0.x); af[i][1] = f2bs(x0.y);
                af[i][2] = f2bs(x0.z); af[i][3] = f2bs(x0.w);
                af[i][4] = f2bs(x1.x); af[i][5] = f2bs(x1.y);
                af[i][6] = f2bs(x1.z); af[i][7] = f2bs(x1.w);
            } else {
                af[i] = *(const short8*)&cA[rA * 32 + 8 * bswz(rA, q)];
            }
        }
#pragma unroll
        for (int j = 0; j < NFRAG; ++j) {
            const int rB = wc * (16 * NFRAG) + j * 16 + ml;
            bfr[j] = *(const short8*)&cB[rB * 32 + 8 * bswz(rB, q)];
        }
    };

    auto mfma = [&](short8 (&af)[4], short8 (&bfr)[NFRAG]) {
#pragma unroll
        for (int mi = 0; mi < 4; ++mi)
#pragma unroll
            for (int nj = 0; nj < NFRAG; ++nj)
                acc[mi][nj] = __builtin_amdgcn_mfma_f32_16x16x32_bf16(
                    af[mi], bfr[nj], acc[mi][nj], 0, 0, 0);
    };

    const int nk = kLen / BK;        // call sites: 16, 32 (all >= 3)
    stage(0); stage(1);              // 2 tiles in flight
    int cur = 0;
    for (int t = 0; t < nk - 2; ++t) {
        s_wait_vmcnt<L>();           // tile t landed; t+1 in flight
        __builtin_amdgcn_s_barrier();
        short8 af_[4], bf_[NFRAG];
        frags(cur, af_, bf_);
        int nb = cur + 2; nb = (nb >= 3) ? nb - 3 : nb;
        stage(nb);                   // tile t+2 -> buf (t+2)%3
        mfma(af_, bf_);
        asm volatile("s_waitcnt lgkmcnt(0)" ::: "memory");
        cur = (cur == 2) ? 0 : cur + 1;
    }
    {   // t = nk-2: tile nk-2 landed, nk-1 in flight
        s_wait_vmcnt<L>();
        __builtin_amdgcn_s_barrier();
        short8 af_[4], bf_[NFRAG];
        frags(cur, af_, bf_);
        mfma(af_, bf_);
        cur = (cur == 2) ? 0 : cur + 1;
    }
    {   // t = nk-1
        s_wait_vmcnt<0>();
        __builtin_amdgcn_s_barrier();
        short8 af_[4], bf_[NFRAG];
        frags(cur, af_, bf_);
        mfma(af_, bf_);
    }

    // epilogue: C/D layout col=lane&15, row=(lane>>4)*4+r (m89-verified)
#pragma unroll
    for (int mi = 0; mi < 4; ++mi)
#pragma unroll
        for (int nj = 0; nj < NFRAG; ++nj)
#pragma unroll
            for (int r = 0; r < 4; ++r) {
                int row = m0 + wr * 64 + mi * 16 + q * 4 + r;
                int col = n0 + wc * (16 * NFRAG) + nj * 16 + ml;
                if constexpr (MODE == 1) {
                    float* Cf = (float*)Cv + (size_t)batch * sC;
                    atomicAdd(&Cf[(size_t)row * N + col], acc[mi][nj][r]);
                } else if constexpr (MODE == 0) {
                    ushort* Cb = (ushort*)Cv + (size_t)batch * sC;
                    Cb[(size_t)row * N + col] = (ushort)f2bs(acc[mi][nj][r]);
                } else {
                    float* Cf = (float*)Cv + (size_t)batch * sC;
                    Cf[(size_t)row * N + col] = acc[mi][nj][r];
                }
            }
}

// ---------------------------------------------------------------
// fp32 I/O.  O = ((X W^T) X^T) X == X * (W^T (X^T X))   [associative]
//   Gf = Xt * Xt^T   (split-K=4, fp32 atomic)     Xt = bf16(X)^T
//   Mt = Gf * Wt^T   (A fp32 staged, bf16 store)  Wt = bf16(W)^T
//   O  = X * Mt^T    (fp32 store; A = Xb bf16 if ws fits, else X fp32)
// d_out scratch (dead before step 7 overwrites):
//   Xt bf16 @0 (16M) | Gf f32 @16M (8M) | Wt @28M (2M)
// ws: [Xb bf16 16M if ws_size>=20M] + Mt bf16 4M.
// Round 8: z-aware XCD-contiguous remap; NFRAG=4 on steps 4/7 (best
// measured geometry); step 6 direct Gf->Mt (6 launches total).
// ---------------------------------------------------------------
extern "C" void kernel_launch(void* const* d_in, const int* in_sizes, int n_in,
                              void* d_out, int out_size, void* d_ws, size_t ws_size,
                              hipStream_t stream)
{
    const int B = 2, N = 4096, D = 1024;
    const float* X = (const float*)d_in[0];   // [B][N][D] fp32
    const float* W = (const float*)d_in[1];   // [D][D]    fp32
    float* out = (float*)d_out;               // [B][N][D] fp32

    char* ob = (char*)d_out;
    char* ws = (char*)d_ws;
    ushort* Xt = (ushort*)ob;                  // [B][D][N] bf16, 16 MiB
    float*  Gf = (float*)(ob + (16ll << 20));  // [B][D][D] fp32,  8 MiB
    ushort* Wt = (ushort*)(ob + (28ll << 20)); // [D][D]    bf16,  2 MiB

    const bool bigws = ws_size >= (20ull << 20);
    ushort* Xb = bigws ? (ushort*)ws : nullptr;             // [B][N][D] bf16, 16 MiB
    ushort* Mt = (ushort*)(ws + (bigws ? (16ll << 20) : 0)); // [B][D][D] bf16, 4 MiB

    // 1) Xt[b] = bf16(X[b])^T  (+ Xb = bf16(X) row-major when ws allows)
    transpose_cvt<<<dim3(D / 64, N / 64, B), 256, 0, stream>>>(
        X, Xt, Xb, N, D, (long)N * D, (long)D * N, (long)N * D);
    // 2) Wt = bf16(W)^T
    transpose_cvt<<<dim3(D / 64, D / 64, 1), 256, 0, stream>>>(
        W, Wt, nullptr, D, D, 0, 0, 0);
    // 3) zero split-K accumulator
    (void)hipMemsetAsync(Gf, 0, (size_t)B * D * D * sizeof(float), stream);
    // 4) Gf[b] += Xt[b] * Xt[b]^T   (M=N=D, K=4096, sk=4, BN=128;
    //    512 blocks, 64/XCD => XCD k owns exactly one (batch,chunk))
    gemm_bt<1, 0, 4><<<dim3(D / 128, D / BM, B * 4), 256, 0, stream>>>(
        (const void*)Xt, (const bf16*)Xt, Gf, D, D, N, 4,
        (long)D * N, (long)D * N, (long)D * D);
    // 6) Mt[b] = Gf[b] * Wt^T   (M=N=K=D, BN=64, A fp32; 256 blocks)
    gemm_bt<0, 1, 2><<<dim3(D / 64, D / BM, B), 256, 0, stream>>>(
        (const void*)Gf, (const bf16*)Wt, Mt, D, D, D, 1,
        (long)D * D, 0, (long)D * D);
    // 7) O[b] = X[b] * Mt[b]^T  (M=4096, N=D, K=D, BN=128; 512 blocks,
    //    64/XCD => XCD owns a 2MB Xb row-stripe + one batch's Mt)
    if (bigws) {
        gemm_bt<2, 0, 4><<<dim3(D / 128, N / BM, B), 256, 0, stream>>>(
            (const void*)Xb, (const bf16*)Mt, out, N, D, D, 1,
            (long)N * D, (long)D * D, (long)N * D);
    } else {
        gemm_bt<2, 1, 4><<<dim3(D / 128, N / BM, B), 256, 0, stream>>>(
            (const void*)X, (const bf16*)Mt, out, N, D, D, 1,
            (long)N * D, (long)D * D, (long)N * D);
    }
}